// Round 5
// baseline (258.060 us; speedup 1.0000x reference)
//
#include <hip/hip_runtime.h>
#include <stdint.h>
#include <math.h>

// MultiHeadAttention: B=2, S=2048, D=1024, H=16, DH=64
// R5: async prefetch pipelines. All hot kernels restructured to
//   barrier -> issue stage(t+1) -> compute(t)
// with double-buffered LDS, so global_load_lds prefetch stays in flight across
// compute and is drained by the NEXT iteration's barrier (one barrier/iter).

typedef __attribute__((ext_vector_type(8))) short short8;
typedef __attribute__((ext_vector_type(4))) float floatx4;

#define LOG2E 1.44269504088896340736f

__device__ __forceinline__ unsigned short f32_bf16(float f) {
  union { float f; unsigned u; } c; c.f = f;
  return (unsigned short)((c.u + 0x7FFFu + ((c.u >> 16) & 1u)) >> 16);
}
__device__ __forceinline__ float bf16_f32(unsigned short u) {
  union { unsigned u; float f; } c; c.u = ((unsigned)u) << 16;
  return c.f;
}
__device__ __forceinline__ void gld16(const void* g, void* l) {
  __builtin_amdgcn_global_load_lds((const __attribute__((address_space(1))) void*)g,
                                   (__attribute__((address_space(3))) void*)l, 16, 0, 0);
}

// ---------------- pre-passes ----------------

__global__ __launch_bounds__(256) void cvt3_kernel(
    const float* __restrict__ a, const float* __restrict__ b, const float* __restrict__ c,
    unsigned short* __restrict__ oa, unsigned short* __restrict__ ob, unsigned short* __restrict__ oc,
    const int* __restrict__ mask, float* __restrict__ mb, int n4) {
  int i = blockIdx.x * 256 + threadIdx.x;
  if (blockIdx.y == 0 && blockIdx.x < 16) {  // fused mask bias (4096 elems)
    int j = blockIdx.x * 256 + threadIdx.x;
    mb[j] = (mask[j] == 0) ? (-1.0e9f * LOG2E) : 0.0f;
  }
  if (i >= n4) return;
  const float* in; unsigned short* out;
  if (blockIdx.y == 0) { in = a; out = oa; }
  else if (blockIdx.y == 1) { in = b; out = ob; }
  else { in = c; out = oc; }
  float4 v = reinterpret_cast<const float4*>(in)[i];
  ushort4 o;
  o.x = f32_bf16(v.x); o.y = f32_bf16(v.y); o.z = f32_bf16(v.z); o.w = f32_bf16(v.w);
  reinterpret_cast<ushort4*>(out)[i] = o;
}

// merged weight transposes: z<48 -> per-head qkv [16][1024][64]; z==48 -> Wo [1024][1024]
__global__ __launch_bounds__(256) void transpose_w_kernel(
    const float* __restrict__ w0, const float* __restrict__ w1, const float* __restrict__ w2,
    const float* __restrict__ wo,
    unsigned short* __restrict__ o0, unsigned short* __restrict__ o1, unsigned short* __restrict__ o2,
    unsigned short* __restrict__ oo) {
  __shared__ float t[32][33];
  const int tx = threadIdx.x & 31, ty = threadIdx.x >> 5;
  const int zb = blockIdx.z;
  const float* in; unsigned short* out; int R, C, z, r0, c0;
  if (zb < 48) {
    if (blockIdx.y >= 2) return;
    const int sel = zb >> 4; z = zb & 15;
    in = (sel == 0) ? w0 : (sel == 1) ? w1 : w2;
    out = (sel == 0) ? o0 : (sel == 1) ? o1 : o2;
    R = 1024; C = 64;
  } else {
    in = wo; out = oo; R = 1024; C = 1024; z = 0;
  }
  r0 = blockIdx.x * 32; c0 = blockIdx.y * 32;
  const float* inp = in + (size_t)z * R * C;
  #pragma unroll
  for (int j = 0; j < 4; ++j)
    t[ty + j * 8][tx] = inp[(size_t)(r0 + ty + j * 8) * C + c0 + tx];
  __syncthreads();
  #pragma unroll
  for (int j = 0; j < 4; ++j)
    out[((size_t)z * C + c0 + ty + j * 8) * R + r0 + tx] = f32_bf16(t[tx][ty + j * 8]);
}

// ---------------- GEMM core 128x128, prefetch-pipelined ----------------
// As/Bs are [2][128*32] double buffers. One barrier per K-iter; stage(t+1)
// issued after the barrier so it overlaps compute(t).

__device__ __forceinline__ void gemm_core(
    const unsigned short* __restrict__ A, const unsigned short* __restrict__ Bt,
    int K, int blockM, int blockN,
    unsigned short* As, unsigned short* Bs, floatx4 acc[4][4]) {
  const int tid = threadIdx.x;
  const int w = tid >> 6;
  const int lane = tid & 63;
  const int quad = lane >> 4, l15 = lane & 15;
  const int wm = w & 1, wn = w >> 1;
  const int srow = lane >> 2;
  const int scol = (lane & 3) * 8;

  #pragma unroll
  for (int mi = 0; mi < 4; ++mi)
    #pragma unroll
    for (int ni = 0; ni < 4; ++ni)
      acc[mi][ni] = (floatx4){0.f, 0.f, 0.f, 0.f};

  const unsigned short* Arow = A + (size_t)blockM * K + (size_t)srow * K + scol;
  const unsigned short* Brow = Bt + (size_t)blockN * K + (size_t)srow * K + scol;

  auto stage = [&](int k0, int buf) {
    unsigned short* Asb = As + buf * (128 * 32);
    unsigned short* Bsb = Bs + buf * (128 * 32);
    #pragma unroll
    for (int i = 0; i < 2; ++i) {
      int row = w * 32 + i * 16;
      gld16(Arow + (size_t)row * K + k0, Asb + row * 32);
      gld16(Brow + (size_t)row * K + k0, Bsb + row * 32);
    }
  };

  const int iters = K >> 5;
  stage(0, 0);
  for (int it = 0; it < iters; ++it) {
    __syncthreads();  // drains stage(it); publishes buf it&1
    if (it + 1 < iters) stage((it + 1) * 32, (it + 1) & 1);
    const unsigned short* Asb = As + (it & 1) * (128 * 32);
    const unsigned short* Bsb = Bs + (it & 1) * (128 * 32);
    short8 bf[4];
    #pragma unroll
    for (int ni = 0; ni < 4; ++ni)
      bf[ni] = *(const short8*)(Bsb + (wn * 64 + ni * 16 + l15) * 32 + quad * 8);
    #pragma unroll
    for (int mi = 0; mi < 4; ++mi) {
      short8 af = *(const short8*)(Asb + (wm * 64 + mi * 16 + l15) * 32 + quad * 8);
      #pragma unroll
      for (int ni = 0; ni < 4; ++ni)
        acc[mi][ni] = __builtin_amdgcn_mfma_f32_16x16x32_bf16(af, bf[ni], acc[mi][ni], 0, 0, 0);
    }
  }
}

// projections. z=0/1: Q/K -> [BH][S][64]. z=2: transposed orientation, V^T -> [BH][64][S].
__global__ __launch_bounds__(256) void gemm_proj_kernel(
    const unsigned short* __restrict__ qin, const unsigned short* __restrict__ kin,
    const unsigned short* __restrict__ vin,
    const unsigned short* __restrict__ WqT, const unsigned short* __restrict__ WkT,
    const unsigned short* __restrict__ WvT,
    const float* __restrict__ bq, const float* __restrict__ bk, const float* __restrict__ bv,
    unsigned short* __restrict__ Qp, unsigned short* __restrict__ Kp,
    unsigned short* __restrict__ Vt) {
  __shared__ unsigned short As[2][128 * 32];
  __shared__ unsigned short Bs[2][128 * 32];
  const int z = blockIdx.y, bx = blockIdx.x;
  const unsigned short *A, *Bt;
  const float* bias;
  int blockM, blockN;
  if (z < 2) {
    blockN = (bx & 7) * 128; blockM = (bx >> 3) * 128;
    A = z ? kin : qin; Bt = z ? WkT : WqT; bias = z ? bk : bq;
  } else {
    blockM = (bx & 7) * 128; blockN = (bx >> 3) * 128;
    A = WvT; Bt = vin; bias = bv;
  }
  floatx4 acc[4][4];
  gemm_core(A, Bt, 1024, blockM, blockN, As[0], Bs[0], acc);

  const int tid = threadIdx.x, w = tid >> 6, lane = tid & 63;
  const int quad = lane >> 4, l15 = lane & 15;
  const int wm = w & 1, wn = w >> 1;

  if (z < 2) {
    unsigned short* outp = z ? Kp : Qp;
    #pragma unroll
    for (int mi = 0; mi < 4; ++mi)
      #pragma unroll
      for (int ni = 0; ni < 4; ++ni) {
        const int n = blockN + wn * 64 + ni * 16 + l15;
        const int h = n >> 6, e = n & 63;
        const float bvv = bias[n];
        #pragma unroll
        for (int r = 0; r < 4; ++r) {
          const int m = blockM + wm * 64 + mi * 16 + quad * 4 + r;
          const int b = m >> 11, s = m & 2047;
          outp[(((size_t)b * 16 + h) * 2048 + s) * 64 + e] = f32_bf16(acc[mi][ni][r] + bvv);
        }
      }
  } else {
    #pragma unroll
    for (int mi = 0; mi < 4; ++mi) {
      float br[4];
      #pragma unroll
      for (int r = 0; r < 4; ++r)
        br[r] = bias[blockM + wm * 64 + mi * 16 + quad * 4 + r];
      #pragma unroll
      for (int ni = 0; ni < 4; ++ni) {
        const int n = blockN + wn * 64 + ni * 16 + l15;   // global s-index
        const int b = n >> 11, s = n & 2047;
        #pragma unroll
        for (int r = 0; r < 4; ++r) {
          const int m = blockM + wm * 64 + mi * 16 + quad * 4 + r;  // global e-index
          const int h = m >> 6, e = m & 63;
          Vt[(((size_t)b * 16 + h) * 64 + e) * 2048 + s] = f32_bf16(acc[mi][ni][r] + br[r]);
        }
      }
    }
  }
}

// output projection, tile 128M x 64N -> 512 blocks (2/CU), prefetch-pipelined
__global__ __launch_bounds__(256) void gemm_out_kernel(
    const unsigned short* __restrict__ A, const unsigned short* __restrict__ Bt,
    const float* __restrict__ bias, float* __restrict__ out, int K, int N) {
  __shared__ unsigned short As[2][128 * 32];
  __shared__ unsigned short Bs[2][64 * 32];
  const int tid = threadIdx.x;
  const int w = tid >> 6, lane = tid & 63;
  const int quad = lane >> 4, l15 = lane & 15;
  const int wm = w & 1, wn = w >> 1;
  const int srow = lane >> 2;
  const int scol = (lane & 3) * 8;
  const int blockN = blockIdx.x * 64, blockM = blockIdx.y * 128;

  floatx4 acc[4][2];
  #pragma unroll
  for (int mi = 0; mi < 4; ++mi)
    #pragma unroll
    for (int ni = 0; ni < 2; ++ni)
      acc[mi][ni] = (floatx4){0.f, 0.f, 0.f, 0.f};

  const unsigned short* Arow = A + (size_t)blockM * K + (size_t)srow * K + scol;
  const unsigned short* Brow = Bt + (size_t)blockN * K + (size_t)srow * K + scol;

  auto stage = [&](int k0, int buf) {
    #pragma unroll
    for (int i = 0; i < 2; ++i) {
      int row = w * 32 + i * 16;
      gld16(Arow + (size_t)row * K + k0, As[buf] + row * 32);
    }
    gld16(Brow + (size_t)(w * 16) * K + k0, Bs[buf] + (w * 16) * 32);
  };

  const int iters = K >> 5;
  stage(0, 0);
  for (int it = 0; it < iters; ++it) {
    __syncthreads();
    if (it + 1 < iters) stage((it + 1) * 32, (it + 1) & 1);
    const unsigned short* Asb = As[it & 1];
    const unsigned short* Bsb = Bs[it & 1];
    short8 bf[2];
    #pragma unroll
    for (int ni = 0; ni < 2; ++ni)
      bf[ni] = *(const short8*)(Bsb + (wn * 32 + ni * 16 + l15) * 32 + quad * 8);
    #pragma unroll
    for (int mi = 0; mi < 4; ++mi) {
      short8 af = *(const short8*)(Asb + (wm * 64 + mi * 16 + l15) * 32 + quad * 8);
      #pragma unroll
      for (int ni = 0; ni < 2; ++ni)
        acc[mi][ni] = __builtin_amdgcn_mfma_f32_16x16x32_bf16(af, bf[ni], acc[mi][ni], 0, 0, 0);
    }
  }

  #pragma unroll
  for (int mi = 0; mi < 4; ++mi)
    #pragma unroll
    for (int ni = 0; ni < 2; ++ni) {
      const int n = blockN + wn * 32 + ni * 16 + l15;
      const float bv = bias[n];
      #pragma unroll
      for (int r = 0; r < 4; ++r) {
        const int m = blockM + wm * 64 + mi * 16 + quad * 4 + r;
        out[(size_t)m * N + n] = acc[mi][ni][r] + bv;
      }
    }
}

// ---------------- flash attention, prefetch-pipelined ----------------
// Q,K: bf16 [BH][S][64]; Vt: bf16 [BH][64][S]; ctx: bf16 [B][S][1024]
// XOR chunk swizzle on all LDS tiles. No running max. l via ones-column MFMA.
// K/V tiles double-buffered; stage(t+1) issued after barrier, overlaps compute(t).

__global__ __launch_bounds__(256) void attn_kernel(
    const unsigned short* __restrict__ Q, const unsigned short* __restrict__ Kg,
    const unsigned short* __restrict__ Vt, const float* __restrict__ maskAdd,
    unsigned short* __restrict__ ctx) {
  const int S = 2048;
  const int tid = threadIdx.x;
  const int w = tid >> 6, lane = tid & 63, quad = lane >> 4, l15 = lane & 15;
  const int qb = blockIdx.x, bh = blockIdx.y;
  const int b = bh >> 4, h = bh & 15;
  const int q0 = qb * 128;

  __shared__ unsigned short Ks[2][128 * 64];   // [key][e], swizzled, 8 chunks/row
  __shared__ unsigned short Vs[2][64 * 128];   // [e][key], swizzled, 16 chunks/row
  __shared__ unsigned short Ps[4][32 * 64];    // per-wave [q][key64], swizzled
  unsigned short* Pw = Ps[w];

  const unsigned short* Qb = Q + (size_t)bh * S * 64;
  const unsigned short* Kb = Kg + (size_t)bh * S * 64;
  const unsigned short* Vb = Vt + (size_t)bh * 64 * S;
  const float* mb = maskAdd + (size_t)b * S;

  // Q fragments, pre-scaled by 0.125 * log2(e)
  const float qs = 0.125f * LOG2E;
  short8 qf[2][2];
  #pragma unroll
  for (int mi = 0; mi < 2; ++mi)
    #pragma unroll
    for (int kq = 0; kq < 2; ++kq) {
      short8 v = *(const short8*)(Qb + (size_t)(q0 + w * 32 + mi * 16 + l15) * 64 + kq * 32 + quad * 8);
      #pragma unroll
      for (int j = 0; j < 8; ++j)
        v[j] = (short)f32_bf16(bf16_f32((unsigned short)v[j]) * qs);
      qf[mi][kq] = v;
    }

  short8 onesf;
  #pragma unroll
  for (int j = 0; j < 8; ++j) onesf[j] = (short)0x3F80;  // bf16 1.0

  floatx4 O[2][4], ls[2];
  #pragma unroll
  for (int mi = 0; mi < 2; ++mi) {
    #pragma unroll
    for (int ne = 0; ne < 4; ++ne) O[mi][ne] = (floatx4){0.f, 0.f, 0.f, 0.f};
    ls[mi] = (floatx4){0.f, 0.f, 0.f, 0.f};
  }

  auto stage_kv = [&](int t, int buf) {
    const int kv0 = t * 128;
    #pragma unroll
    for (int i = 0; i < 4; ++i) {  // K tile, swizzled source chunks
      int r0 = w * 32 + i * 8;
      int row = r0 + (lane >> 3);
      int cg = (lane & 7) ^ (row & 7);
      gld16(Kb + (size_t)(kv0 + row) * 64 + cg * 8, Ks[buf] + r0 * 64);
    }
    #pragma unroll
    for (int i = 0; i < 4; ++i) {  // V tile
      int r0 = w * 16 + i * 4;
      int row = r0 + (lane >> 4);
      int p = lane & 15;
      int cg = (p & 8) | ((p & 7) ^ (row & 7));
      gld16(Vb + (size_t)row * S + kv0 + cg * 8, Vs[buf] + r0 * 128);
    }
  };

  stage_kv(0, 0);
  for (int t = 0; t < 16; ++t) {
    const int kv0 = t * 128;
    __syncthreads();  // drains stage(t); publishes buf t&1
    // mask loads first so their waitcnt doesn't drain the prefetch below
    float ma[8];
    #pragma unroll
    for (int ni = 0; ni < 8; ++ni) ma[ni] = mb[kv0 + ni * 16 + l15];
    if (t + 1 < 16) stage_kv(t + 1, (t + 1) & 1);
    const unsigned short* Ksb = Ks[t & 1];
    const unsigned short* Vsb = Vs[t & 1];

    #pragma unroll
    for (int ph = 0; ph < 2; ++ph) {
      floatx4 sc[2][4];
      #pragma unroll
      for (int ni = 0; ni < 4; ++ni) {
        const int key = (ph * 4 + ni) * 16 + l15;
        short8 kf0 = *(const short8*)(Ksb + key * 64 + ((quad) ^ (l15 & 7)) * 8);
        short8 kf1 = *(const short8*)(Ksb + key * 64 + ((4 + quad) ^ (l15 & 7)) * 8);
        #pragma unroll
        for (int mi = 0; mi < 2; ++mi) {
          floatx4 s = (floatx4){0.f, 0.f, 0.f, 0.f};
          s = __builtin_amdgcn_mfma_f32_16x16x32_bf16(qf[mi][0], kf0, s, 0, 0, 0);
          s = __builtin_amdgcn_mfma_f32_16x16x32_bf16(qf[mi][1], kf1, s, 0, 0, 0);
          sc[mi][ni] = s;
        }
      }
      // p = exp2(sc + mask), bf16-truncated into swizzled Pw (wave-private)
      #pragma unroll
      for (int mi = 0; mi < 2; ++mi)
        #pragma unroll
        for (int r = 0; r < 4; ++r) {
          const int row = mi * 16 + quad * 4 + r;
          const int g = (row + (row >> 3)) & 7;
          #pragma unroll
          for (int ni = 0; ni < 4; ++ni) {
            float p = __builtin_amdgcn_exp2f(sc[mi][ni][r] + ma[ph * 4 + ni]);
            union { float f; unsigned u; } c; c.f = p;
            const int ch = (ni * 2 + (l15 >> 3)) ^ g;
            Pw[row * 64 + (ch & 7) * 8 + (l15 & 7)] = (unsigned short)(c.u >> 16);
          }
        }
      // PV + row-sum
      #pragma unroll
      for (int kkl = 0; kkl < 2; ++kkl) {
        const int kk = ph * 2 + kkl;
        short8 pfr[2], vf[4];
        #pragma unroll
        for (int mi = 0; mi < 2; ++mi) {
          const int gp = (2 * mi + l15 + (l15 >> 3)) & 7;
          pfr[mi] = *(const short8*)(Pw + (mi * 16 + l15) * 64 + ((kkl * 4 + quad) ^ gp) * 8);
        }
        #pragma unroll
        for (int ne = 0; ne < 4; ++ne) {
          const int c = kk * 4 + quad;
          vf[ne] = *(const short8*)(Vsb + (ne * 16 + l15) * 128 + ((c & 8) | ((c & 7) ^ (l15 & 7))) * 8);
        }
        #pragma unroll
        for (int mi = 0; mi < 2; ++mi) {
          #pragma unroll
          for (int ne = 0; ne < 4; ++ne)
            O[mi][ne] = __builtin_amdgcn_mfma_f32_16x16x32_bf16(pfr[mi], vf[ne], O[mi][ne], 0, 0, 0);
          ls[mi] = __builtin_amdgcn_mfma_f32_16x16x32_bf16(pfr[mi], onesf, ls[mi], 0, 0, 0);
        }
      }
    }
  }

  // epilogue: ctx[b][s][h*64+e] = O / l
  #pragma unroll
  for (int mi = 0; mi < 2; ++mi)
    #pragma unroll
    for (int r = 0; r < 4; ++r) {
      const float inv = __builtin_amdgcn_rcpf(ls[mi][r]);
      const int s = q0 + w * 32 + mi * 16 + quad * 4 + r;
      #pragma unroll
      for (int ne = 0; ne < 4; ++ne)
        ctx[((size_t)b * S + s) * 1024 + h * 64 + ne * 16 + l15] = f32_bf16(O[mi][ne][r] * inv);
    }
}

// ---------------- host ----------------

extern "C" void kernel_launch(void* const* d_in, const int* in_sizes, int n_in,
                              void* d_out, int out_size, void* d_ws, size_t ws_size,
                              hipStream_t stream) {
  const float* query = (const float*)d_in[0];
  const float* key   = (const float*)d_in[1];
  const float* value = (const float*)d_in[2];
  const int*   mask  = (const int*)d_in[3];
  const float* Wq = (const float*)d_in[4];
  const float* bq = (const float*)d_in[5];
  const float* Wk = (const float*)d_in[6];
  const float* bk = (const float*)d_in[7];
  const float* Wv = (const float*)d_in[8];
  const float* bv = (const float*)d_in[9];
  const float* Wo = (const float*)d_in[10];
  const float* bo = (const float*)d_in[11];
  float* out = (float*)d_out;

  char* ws = (char*)d_ws;
  const size_t MB = 1024 * 1024;
  unsigned short* qin  = (unsigned short*)(ws + 0);        // 8MB
  unsigned short* kin  = (unsigned short*)(ws + 8 * MB);   // 8MB
  unsigned short* vin  = (unsigned short*)(ws + 16 * MB);  // 8MB
  unsigned short* WqT  = (unsigned short*)(ws + 24 * MB);  // 2MB
  unsigned short* WkT  = (unsigned short*)(ws + 26 * MB);
  unsigned short* WvT  = (unsigned short*)(ws + 28 * MB);
  unsigned short* WoT  = (unsigned short*)(ws + 30 * MB);
  unsigned short* Qp   = (unsigned short*)(ws + 32 * MB);  // 8MB [BH][S][64]
  unsigned short* Kp   = (unsigned short*)(ws + 40 * MB);  // 8MB [BH][S][64]
  unsigned short* Vt   = (unsigned short*)(ws + 48 * MB);  // 8MB [BH][64][S]
  float* maskAdd       = (float*)(ws + 56 * MB);           // 16KB
  unsigned short* ctxb = qin;  // alias: qin consumed by proj before attn writes ctx

  cvt3_kernel<<<dim3(4096, 3), 256, 0, stream>>>(query, key, value, qin, kin, vin,
                                                 mask, maskAdd, 1048576);
  transpose_w_kernel<<<dim3(32, 32, 49), 256, 0, stream>>>(Wq, Wk, Wv, Wo, WqT, WkT, WvT, WoT);
  gemm_proj_kernel<<<dim3(256, 3), 256, 0, stream>>>(qin, kin, vin, WqT, WkT, WvT,
                                                     bq, bk, bv, Qp, Kp, Vt);
  attn_kernel<<<dim3(16, 32), 256, 0, stream>>>(Qp, Kp, Vt, maskAdd, ctxb);
  gemm_out_kernel<<<dim3(16, 32), 256, 0, stream>>>(ctxb, WoT, bo, out, 1024, 1024);
}

// Round 6
// 242.122 us; speedup vs baseline: 1.0658x; 1.0658x over previous
//
#include <hip/hip_runtime.h>
#include <stdint.h>
#include <math.h>

// MultiHeadAttention: B=2, S=2048, D=1024, H=16, DH=64
// R6: XCD-clustered block swizzles (blocks sharing the big operand get
// stride-8 linear IDs -> same XCD L2) for gemm_proj / attn / gemm_out;
// cvt3+transpose_w+mask fused into one prep kernel.

typedef __attribute__((ext_vector_type(8))) short short8;
typedef __attribute__((ext_vector_type(4))) float floatx4;

#define LOG2E 1.44269504088896340736f

__device__ __forceinline__ unsigned short f32_bf16(float f) {
  union { float f; unsigned u; } c; c.f = f;
  return (unsigned short)((c.u + 0x7FFFu + ((c.u >> 16) & 1u)) >> 16);
}
__device__ __forceinline__ float bf16_f32(unsigned short u) {
  union { unsigned u; float f; } c; c.u = ((unsigned)u) << 16;
  return c.f;
}
__device__ __forceinline__ void gld16(const void* g, void* l) {
  __builtin_amdgcn_global_load_lds((const __attribute__((address_space(1))) void*)g,
                                   (__attribute__((address_space(3))) void*)l, 16, 0, 0);
}

// ---------------- prep: cvt inputs + weight transposes + mask, one launch ----------------
// grid (4096, 4): y=0..2 -> cvt q/k/v (y==0 also mask); y=3 -> weight transposes
// (bx<3072: per-head qkv [16][1024][64]; else Wo [1024][1024]).

__global__ __launch_bounds__(256) void prep_kernel(
    const float* __restrict__ qf, const float* __restrict__ kf, const float* __restrict__ vf,
    const float* __restrict__ w0, const float* __restrict__ w1, const float* __restrict__ w2,
    const float* __restrict__ wo, const int* __restrict__ mask,
    unsigned short* __restrict__ oq, unsigned short* __restrict__ ok, unsigned short* __restrict__ ov,
    unsigned short* __restrict__ o0, unsigned short* __restrict__ o1, unsigned short* __restrict__ o2,
    unsigned short* __restrict__ oo, float* __restrict__ mb) {
  __shared__ float t[32][33];
  const int y = blockIdx.y, bx = blockIdx.x;
  if (y < 3) {
    if (y == 0 && bx < 16) {
      int j = bx * 256 + threadIdx.x;
      mb[j] = (mask[j] == 0) ? (-1.0e9f * LOG2E) : 0.0f;
    }
    const float* in = (y == 0) ? qf : (y == 1) ? kf : vf;
    unsigned short* out = (y == 0) ? oq : (y == 1) ? ok : ov;
    int i = bx * 256 + threadIdx.x;
    float4 v = reinterpret_cast<const float4*>(in)[i];
    ushort4 o;
    o.x = f32_bf16(v.x); o.y = f32_bf16(v.y); o.z = f32_bf16(v.z); o.w = f32_bf16(v.w);
    reinterpret_cast<ushort4*>(out)[i] = o;
    return;
  }
  // transposes
  const int tx = threadIdx.x & 31, ty = threadIdx.x >> 5;
  const float* in; unsigned short* out; int R, C, z, r0, c0;
  if (bx < 3072) {
    const int zb = bx >> 6, rem = bx & 63;
    const int sel = zb >> 4; z = zb & 15;
    in = (sel == 0) ? w0 : (sel == 1) ? w1 : w2;
    out = (sel == 0) ? o0 : (sel == 1) ? o1 : o2;
    R = 1024; C = 64; r0 = (rem >> 1) * 32; c0 = (rem & 1) * 32;
  } else {
    const int t2 = bx - 3072;
    in = wo; out = oo; R = 1024; C = 1024; z = 0;
    r0 = (t2 >> 5) * 32; c0 = (t2 & 31) * 32;
  }
  const float* inp = in + (size_t)z * R * C;
  #pragma unroll
  for (int j = 0; j < 4; ++j)
    t[ty + j * 8][tx] = inp[(size_t)(r0 + ty + j * 8) * C + c0 + tx];
  __syncthreads();
  #pragma unroll
  for (int j = 0; j < 4; ++j)
    out[((size_t)z * C + c0 + ty + j * 8) * R + r0 + tx] = f32_bf16(t[tx][ty + j * 8]);
}

// ---------------- GEMM core 128x128, prefetch-pipelined ----------------

__device__ __forceinline__ void gemm_core(
    const unsigned short* __restrict__ A, const unsigned short* __restrict__ Bt,
    int K, int blockM, int blockN,
    unsigned short* As, unsigned short* Bs, floatx4 acc[4][4]) {
  const int tid = threadIdx.x;
  const int w = tid >> 6;
  const int lane = tid & 63;
  const int quad = lane >> 4, l15 = lane & 15;
  const int wm = w & 1, wn = w >> 1;
  const int srow = lane >> 2;
  const int scol = (lane & 3) * 8;

  #pragma unroll
  for (int mi = 0; mi < 4; ++mi)
    #pragma unroll
    for (int ni = 0; ni < 4; ++ni)
      acc[mi][ni] = (floatx4){0.f, 0.f, 0.f, 0.f};

  const unsigned short* Arow = A + (size_t)blockM * K + (size_t)srow * K + scol;
  const unsigned short* Brow = Bt + (size_t)blockN * K + (size_t)srow * K + scol;

  auto stage = [&](int k0, int buf) {
    unsigned short* Asb = As + buf * (128 * 32);
    unsigned short* Bsb = Bs + buf * (128 * 32);
    #pragma unroll
    for (int i = 0; i < 2; ++i) {
      int row = w * 32 + i * 16;
      gld16(Arow + (size_t)row * K + k0, Asb + row * 32);
      gld16(Brow + (size_t)row * K + k0, Bsb + row * 32);
    }
  };

  const int iters = K >> 5;
  stage(0, 0);
  for (int it = 0; it < iters; ++it) {
    __syncthreads();  // drains stage(it); publishes buf it&1
    if (it + 1 < iters) stage((it + 1) * 32, (it + 1) & 1);
    const unsigned short* Asb = As + (it & 1) * (128 * 32);
    const unsigned short* Bsb = Bs + (it & 1) * (128 * 32);
    short8 bf[4];
    #pragma unroll
    for (int ni = 0; ni < 4; ++ni)
      bf[ni] = *(const short8*)(Bsb + (wn * 64 + ni * 16 + l15) * 32 + quad * 8);
    #pragma unroll
    for (int mi = 0; mi < 4; ++mi) {
      short8 af = *(const short8*)(Asb + (wm * 64 + mi * 16 + l15) * 32 + quad * 8);
      #pragma unroll
      for (int ni = 0; ni < 4; ++ni)
        acc[mi][ni] = __builtin_amdgcn_mfma_f32_16x16x32_bf16(af, bf[ni], acc[mi][ni], 0, 0, 0);
    }
  }
}

// projections. z=0/1: Q/K -> [BH][S][64]. z=2: transposed orientation, V^T -> [BH][64][S].
// XCD swizzle: blocks sharing the stripe-operand get stride-8 bx (same bx%8 -> same XCD).
__global__ __launch_bounds__(256) void gemm_proj_kernel(
    const unsigned short* __restrict__ qin, const unsigned short* __restrict__ kin,
    const unsigned short* __restrict__ vin,
    const unsigned short* __restrict__ WqT, const unsigned short* __restrict__ WkT,
    const unsigned short* __restrict__ WvT,
    const float* __restrict__ bq, const float* __restrict__ bk, const float* __restrict__ bv,
    unsigned short* __restrict__ Qp, unsigned short* __restrict__ Kp,
    unsigned short* __restrict__ Vt) {
  __shared__ unsigned short As[2][128 * 32];
  __shared__ unsigned short Bs[2][128 * 32];
  const int z = blockIdx.y, bx = blockIdx.x;
  const int r = bx & 7, j = bx >> 3;
  const unsigned short *A, *Bt;
  const float* bias;
  int blockM, blockN;
  if (z < 2) {
    // A-stripes (activations, 32 of them) clustered: XCD r owns m in {4r..4r+3}
    blockM = (r * 4 + (j & 3)) * 128;   // 0..31
    blockN = (j >> 2) * 128;            // 0..7
    A = z ? kin : qin; Bt = z ? WkT : WqT; bias = z ? bk : bq;
  } else {
    // B-stripes (vin, 32 of them) clustered: XCD r owns n in {4r..4r+3}
    blockN = (r * 4 + (j & 3)) * 128;   // 0..31
    blockM = (j >> 2) * 128;            // 0..7
    A = WvT; Bt = vin; bias = bv;
  }
  floatx4 acc[4][4];
  gemm_core(A, Bt, 1024, blockM, blockN, As[0], Bs[0], acc);

  const int tid = threadIdx.x, w = tid >> 6, lane = tid & 63;
  const int quad = lane >> 4, l15 = lane & 15;
  const int wm = w & 1, wn = w >> 1;

  if (z < 2) {
    unsigned short* outp = z ? Kp : Qp;
    #pragma unroll
    for (int mi = 0; mi < 4; ++mi)
      #pragma unroll
      for (int ni = 0; ni < 4; ++ni) {
        const int n = blockN + wn * 64 + ni * 16 + l15;
        const int h = n >> 6, e = n & 63;
        const float bvv = bias[n];
        #pragma unroll
        for (int rr = 0; rr < 4; ++rr) {
          const int m = blockM + wm * 64 + mi * 16 + quad * 4 + rr;
          const int b = m >> 11, s = m & 2047;
          outp[(((size_t)b * 16 + h) * 2048 + s) * 64 + e] = f32_bf16(acc[mi][ni][rr] + bvv);
        }
      }
  } else {
    #pragma unroll
    for (int mi = 0; mi < 4; ++mi) {
      float br[4];
      #pragma unroll
      for (int rr = 0; rr < 4; ++rr)
        br[rr] = bias[blockM + wm * 64 + mi * 16 + quad * 4 + rr];
      #pragma unroll
      for (int ni = 0; ni < 4; ++ni) {
        const int n = blockN + wn * 64 + ni * 16 + l15;   // global s-index
        const int b = n >> 11, s = n & 2047;
        #pragma unroll
        for (int rr = 0; rr < 4; ++rr) {
          const int m = blockM + wm * 64 + mi * 16 + quad * 4 + rr;  // global e-index
          const int h = m >> 6, e = m & 63;
          Vt[(((size_t)b * 16 + h) * 64 + e) * 2048 + s] = f32_bf16(acc[mi][ni][rr] + br[rr]);
        }
      }
    }
  }
}

// output projection, tile 128M x 64N, 1-D grid 512, XCD-clustered by A-stripe
__global__ __launch_bounds__(256) void gemm_out_kernel(
    const unsigned short* __restrict__ A, const unsigned short* __restrict__ Bt,
    const float* __restrict__ bias, float* __restrict__ out, int K, int N) {
  __shared__ unsigned short As[2][128 * 32];
  __shared__ unsigned short Bs[2][64 * 32];
  const int tid = threadIdx.x;
  const int w = tid >> 6, lane = tid & 63;
  const int quad = lane >> 4, l15 = lane & 15;
  const int wm = w & 1, wn = w >> 1;
  const int srow = lane >> 2;
  const int scol = (lane & 3) * 8;
  const int l = blockIdx.x, r = l & 7, j = l >> 3;          // j: 0..63
  const int blockM = (r * 4 + (j & 3)) * 128;               // 32 A-stripes clustered
  const int blockN = (j >> 2) * 64;                         // 0..15

  floatx4 acc[4][2];
  #pragma unroll
  for (int mi = 0; mi < 4; ++mi)
    #pragma unroll
    for (int ni = 0; ni < 2; ++ni)
      acc[mi][ni] = (floatx4){0.f, 0.f, 0.f, 0.f};

  const unsigned short* Arow = A + (size_t)blockM * K + (size_t)srow * K + scol;
  const unsigned short* Brow = Bt + (size_t)blockN * K + (size_t)srow * K + scol;

  auto stage = [&](int k0, int buf) {
    #pragma unroll
    for (int i = 0; i < 2; ++i) {
      int row = w * 32 + i * 16;
      gld16(Arow + (size_t)row * K + k0, As[buf] + row * 32);
    }
    gld16(Brow + (size_t)(w * 16) * K + k0, Bs[buf] + (w * 16) * 32);
  };

  const int iters = K >> 5;
  stage(0, 0);
  for (int it = 0; it < iters; ++it) {
    __syncthreads();
    if (it + 1 < iters) stage((it + 1) * 32, (it + 1) & 1);
    const unsigned short* Asb = As[it & 1];
    const unsigned short* Bsb = Bs[it & 1];
    short8 bf[2];
    #pragma unroll
    for (int ni = 0; ni < 2; ++ni)
      bf[ni] = *(const short8*)(Bsb + (wn * 32 + ni * 16 + l15) * 32 + quad * 8);
    #pragma unroll
    for (int mi = 0; mi < 4; ++mi) {
      short8 af = *(const short8*)(Asb + (wm * 64 + mi * 16 + l15) * 32 + quad * 8);
      #pragma unroll
      for (int ni = 0; ni < 2; ++ni)
        acc[mi][ni] = __builtin_amdgcn_mfma_f32_16x16x32_bf16(af, bf[ni], acc[mi][ni], 0, 0, 0);
    }
  }

  #pragma unroll
  for (int mi = 0; mi < 4; ++mi)
    #pragma unroll
    for (int ni = 0; ni < 2; ++ni) {
      const int n = blockN + wn * 32 + ni * 16 + l15;
      const float bv = bias[n];
      #pragma unroll
      for (int rr = 0; rr < 4; ++rr) {
        const int m = blockM + wm * 64 + mi * 16 + quad * 4 + rr;
        out[(size_t)m * N + n] = acc[mi][ni][rr] + bv;
      }
    }
}

// ---------------- flash attention, prefetch-pipelined, XCD-clustered ----------------
// Q,K: bf16 [BH][S][64]; Vt: bf16 [BH][64][S]; ctx: bf16 [B][S][1024]
// 1-D grid 512; the 16 q-blocks of one head get stride-8 IDs -> same XCD L2
// caches that head's K/V (512 KB).

__global__ __launch_bounds__(256) void attn_kernel(
    const unsigned short* __restrict__ Q, const unsigned short* __restrict__ Kg,
    const unsigned short* __restrict__ Vt, const float* __restrict__ maskAdd,
    unsigned short* __restrict__ ctx) {
  const int S = 2048;
  const int tid = threadIdx.x;
  const int w = tid >> 6, lane = tid & 63, quad = lane >> 4, l15 = lane & 15;
  const int l = blockIdx.x, r8 = l & 7, j8 = l >> 3;   // j8: 0..63
  const int bh = r8 * 4 + (j8 & 3);                    // 4 heads per XCD
  const int qb = j8 >> 2;                              // 0..15
  const int b = bh >> 4, h = bh & 15;
  const int q0 = qb * 128;

  __shared__ unsigned short Ks[2][128 * 64];   // [key][e], swizzled, 8 chunks/row
  __shared__ unsigned short Vs[2][64 * 128];   // [e][key], swizzled, 16 chunks/row
  __shared__ unsigned short Ps[4][32 * 64];    // per-wave [q][key64], swizzled
  unsigned short* Pw = Ps[w];

  const unsigned short* Qb = Q + (size_t)bh * S * 64;
  const unsigned short* Kb = Kg + (size_t)bh * S * 64;
  const unsigned short* Vb = Vt + (size_t)bh * 64 * S;
  const float* mb = maskAdd + (size_t)b * S;

  const float qs = 0.125f * LOG2E;
  short8 qf[2][2];
  #pragma unroll
  for (int mi = 0; mi < 2; ++mi)
    #pragma unroll
    for (int kq = 0; kq < 2; ++kq) {
      short8 v = *(const short8*)(Qb + (size_t)(q0 + w * 32 + mi * 16 + l15) * 64 + kq * 32 + quad * 8);
      #pragma unroll
      for (int jj = 0; jj < 8; ++jj)
        v[jj] = (short)f32_bf16(bf16_f32((unsigned short)v[jj]) * qs);
      qf[mi][kq] = v;
    }

  short8 onesf;
  #pragma unroll
  for (int jj = 0; jj < 8; ++jj) onesf[jj] = (short)0x3F80;  // bf16 1.0

  floatx4 O[2][4], ls[2];
  #pragma unroll
  for (int mi = 0; mi < 2; ++mi) {
    #pragma unroll
    for (int ne = 0; ne < 4; ++ne) O[mi][ne] = (floatx4){0.f, 0.f, 0.f, 0.f};
    ls[mi] = (floatx4){0.f, 0.f, 0.f, 0.f};
  }

  auto stage_kv = [&](int t, int buf) {
    const int kv0 = t * 128;
    #pragma unroll
    for (int i = 0; i < 4; ++i) {  // K tile, swizzled source chunks
      int r0 = w * 32 + i * 8;
      int row = r0 + (lane >> 3);
      int cg = (lane & 7) ^ (row & 7);
      gld16(Kb + (size_t)(kv0 + row) * 64 + cg * 8, Ks[buf] + r0 * 64);
    }
    #pragma unroll
    for (int i = 0; i < 4; ++i) {  // V tile
      int r0 = w * 16 + i * 4;
      int row = r0 + (lane >> 4);
      int p = lane & 15;
      int cg = (p & 8) | ((p & 7) ^ (row & 7));
      gld16(Vb + (size_t)row * S + kv0 + cg * 8, Vs[buf] + r0 * 128);
    }
  };

  stage_kv(0, 0);
  for (int t = 0; t < 16; ++t) {
    const int kv0 = t * 128;
    __syncthreads();  // drains stage(t); publishes buf t&1
    float ma[8];
    #pragma unroll
    for (int ni = 0; ni < 8; ++ni) ma[ni] = mb[kv0 + ni * 16 + l15];
    if (t + 1 < 16) stage_kv(t + 1, (t + 1) & 1);
    const unsigned short* Ksb = Ks[t & 1];
    const unsigned short* Vsb = Vs[t & 1];

    #pragma unroll
    for (int ph = 0; ph < 2; ++ph) {
      floatx4 sc[2][4];
      #pragma unroll
      for (int ni = 0; ni < 4; ++ni) {
        const int key = (ph * 4 + ni) * 16 + l15;
        short8 kf0 = *(const short8*)(Ksb + key * 64 + ((quad) ^ (l15 & 7)) * 8);
        short8 kf1 = *(const short8*)(Ksb + key * 64 + ((4 + quad) ^ (l15 & 7)) * 8);
        #pragma unroll
        for (int mi = 0; mi < 2; ++mi) {
          floatx4 s = (floatx4){0.f, 0.f, 0.f, 0.f};
          s = __builtin_amdgcn_mfma_f32_16x16x32_bf16(qf[mi][0], kf0, s, 0, 0, 0);
          s = __builtin_amdgcn_mfma_f32_16x16x32_bf16(qf[mi][1], kf1, s, 0, 0, 0);
          sc[mi][ni] = s;
        }
      }
      #pragma unroll
      for (int mi = 0; mi < 2; ++mi)
        #pragma unroll
        for (int rr = 0; rr < 4; ++rr) {
          const int row = mi * 16 + quad * 4 + rr;
          const int g = (row + (row >> 3)) & 7;
          #pragma unroll
          for (int ni = 0; ni < 4; ++ni) {
            float p = __builtin_amdgcn_exp2f(sc[mi][ni][rr] + ma[ph * 4 + ni]);
            union { float f; unsigned u; } c; c.f = p;
            const int ch = (ni * 2 + (l15 >> 3)) ^ g;
            Pw[row * 64 + (ch & 7) * 8 + (l15 & 7)] = (unsigned short)(c.u >> 16);
          }
        }
      #pragma unroll
      for (int kkl = 0; kkl < 2; ++kkl) {
        const int kk = ph * 2 + kkl;
        short8 pfr[2], vfr[4];
        #pragma unroll
        for (int mi = 0; mi < 2; ++mi) {
          const int gp = (2 * mi + l15 + (l15 >> 3)) & 7;
          pfr[mi] = *(const short8*)(Pw + (mi * 16 + l15) * 64 + ((kkl * 4 + quad) ^ gp) * 8);
        }
        #pragma unroll
        for (int ne = 0; ne < 4; ++ne) {
          const int c = kk * 4 + quad;
          vfr[ne] = *(const short8*)(Vsb + (ne * 16 + l15) * 128 + ((c & 8) | ((c & 7) ^ (l15 & 7))) * 8);
        }
        #pragma unroll
        for (int mi = 0; mi < 2; ++mi) {
          #pragma unroll
          for (int ne = 0; ne < 4; ++ne)
            O[mi][ne] = __builtin_amdgcn_mfma_f32_16x16x32_bf16(pfr[mi], vfr[ne], O[mi][ne], 0, 0, 0);
          ls[mi] = __builtin_amdgcn_mfma_f32_16x16x32_bf16(pfr[mi], onesf, ls[mi], 0, 0, 0);
        }
      }
    }
  }

  // epilogue: ctx[b][s][h*64+e] = O / l
  #pragma unroll
  for (int mi = 0; mi < 2; ++mi)
    #pragma unroll
    for (int rr = 0; rr < 4; ++rr) {
      const float inv = __builtin_amdgcn_rcpf(ls[mi][rr]);
      const int s = q0 + w * 32 + mi * 16 + quad * 4 + rr;
      #pragma unroll
      for (int ne = 0; ne < 4; ++ne)
        ctx[((size_t)b * S + s) * 1024 + h * 64 + ne * 16 + l15] = f32_bf16(O[mi][ne][rr] * inv);
    }
}

// ---------------- host ----------------

extern "C" void kernel_launch(void* const* d_in, const int* in_sizes, int n_in,
                              void* d_out, int out_size, void* d_ws, size_t ws_size,
                              hipStream_t stream) {
  const float* query = (const float*)d_in[0];
  const float* key   = (const float*)d_in[1];
  const float* value = (const float*)d_in[2];
  const int*   mask  = (const int*)d_in[3];
  const float* Wq = (const float*)d_in[4];
  const float* bq = (const float*)d_in[5];
  const float* Wk = (const float*)d_in[6];
  const float* bk = (const float*)d_in[7];
  const float* Wv = (const float*)d_in[8];
  const float* bv = (const float*)d_in[9];
  const float* Wo = (const float*)d_in[10];
  const float* bo = (const float*)d_in[11];
  float* out = (float*)d_out;

  char* ws = (char*)d_ws;
  const size_t MB = 1024 * 1024;
  unsigned short* qin  = (unsigned short*)(ws + 0);        // 8MB
  unsigned short* kin  = (unsigned short*)(ws + 8 * MB);   // 8MB
  unsigned short* vin  = (unsigned short*)(ws + 16 * MB);  // 8MB
  unsigned short* WqT  = (unsigned short*)(ws + 24 * MB);  // 2MB
  unsigned short* WkT  = (unsigned short*)(ws + 26 * MB);
  unsigned short* WvT  = (unsigned short*)(ws + 28 * MB);
  unsigned short* WoT  = (unsigned short*)(ws + 30 * MB);
  unsigned short* Qp   = (unsigned short*)(ws + 32 * MB);  // 8MB [BH][S][64]
  unsigned short* Kp   = (unsigned short*)(ws + 40 * MB);  // 8MB [BH][S][64]
  unsigned short* Vt   = (unsigned short*)(ws + 48 * MB);  // 8MB [BH][64][S]
  float* maskAdd       = (float*)(ws + 56 * MB);           // 16KB
  unsigned short* ctxb = qin;  // alias: qin consumed by proj before attn writes ctx

  prep_kernel<<<dim3(4096, 4), 256, 0, stream>>>(query, key, value, Wq, Wk, Wv, Wo, mask,
                                                 qin, kin, vin, WqT, WkT, WvT, WoT, maskAdd);
  gemm_proj_kernel<<<dim3(256, 3), 256, 0, stream>>>(qin, kin, vin, WqT, WkT, WvT,
                                                     bq, bk, bv, Qp, Kp, Vt);
  attn_kernel<<<dim3(512), 256, 0, stream>>>(Qp, Kp, Vt, maskAdd, ctxb);
  gemm_out_kernel<<<dim3(512), 256, 0, stream>>>(ctxb, WoT, bo, out, 1024, 1024);
}